// Round 1
// baseline (45241.309 us; speedup 1.0000x reference)
//
#include <hip/hip_runtime.h>
#include <hip/hip_bf16.h>

#define L_ 2
#define H_ 1024
#define Z_ 256
#define B_ 128
#define SRC_ 64
#define K_ 48
#define BH_ (B_ * H_)
#define BZ_ (B_ * Z_)
#define BKZ_ ((size_t)B_ * K_ * Z_)
#define KA_ 2304   // lstm0 GEMM K: z(256) | attn(1024) | h0(1024)
#define KB_ 2048   // lstm1 GEMM K: h0n(1024) | h1(1024)
#define NBLK_ 1024 // persistent grid: 4 blocks/CU on 256 CUs
#define GRP_ (NBLK_ / 8)

typedef unsigned short u16;
typedef __attribute__((ext_vector_type(8))) short short8;
typedef __attribute__((ext_vector_type(4))) float f32x4;

// ---------------- static device workspace ----------------
__device__ __align__(16) u16 g_Wc0[4096 * KA_];     // lstm0 weights [4h+g][KA]
__device__ __align__(16) u16 g_Wc1[4096 * KB_];     // lstm1 weights
__device__ __align__(16) u16 g_Wmq[512 * 1024];     // mu/sigma rows interleaved [2z+sel][1024]
__device__ __align__(16) u16 g_Woutb[1024 * 2048];  // Wout bf16
__device__ __align__(16) u16 g_WinT[1024 * 1024];   // Win transposed bf16
__device__ __align__(16) u16 g_ctxb[8192 * 1024];   // context bf16 [B*SRC][H]
__device__ __align__(16) u16 g_ctxW[8192 * 1024];   // ctx @ Wout[:, :H]^T
__device__ __align__(16) u16 g_ctxWin[8192 * 1024]; // ctx @ Win
__device__ __align__(16) u16 g_XA[2][B_ * KA_];     // lstm0 input (dbl-buf): z|attn|h0state
__device__ __align__(16) u16 g_XB[2][B_ * KB_];     // lstm1 input: h0n|h1state
__device__ __align__(16) u16 g_XC[B_ * H_];         // h1n unfrozen (query / musig input)
__device__ float g_pb0[4096], g_pb1[4096], g_pbmq[512], g_wk0[4096];
__device__ float g_cs0[BH_], g_cs1[BH_], g_align[B_ * SRC_];
__device__ float g_cred[B_ * H_];                   // attn q-GEMM staging (fp32)

// barrier state: per-XCD-group counters padded to own cachelines + global gen
__device__ __align__(128) unsigned g_bar_x[8][32];
__device__ __align__(128) unsigned g_bar_g;

__device__ __forceinline__ float sigm(float x) { return 1.0f / (1.0f + expf(-x)); }
__device__ __forceinline__ u16 f2b(float f) {
    union { float f; unsigned u; } x; x.f = f;
    unsigned r = x.u + 0x7fffu + ((x.u >> 16) & 1u);
    return (u16)(r >> 16);
}
__device__ __forceinline__ float b2f(u16 s) {
    union { unsigned u; float f; } x; x.u = ((unsigned)s) << 16;
    return x.f;
}

// monotonic two-level grid barrier (all NBLK_ blocks must call in lockstep order)
__device__ __forceinline__ void gsync(int bid, int bar) {
    __syncthreads();
    if (threadIdx.x == 0) {
        __threadfence();
        unsigned v = __hip_atomic_fetch_add(&g_bar_x[bid & 7][0], 1u,
                                            __ATOMIC_ACQ_REL, __HIP_MEMORY_SCOPE_AGENT);
        if (v == (unsigned)(bar * GRP_ + (GRP_ - 1)))
            __hip_atomic_fetch_add(&g_bar_g, 1u, __ATOMIC_ACQ_REL, __HIP_MEMORY_SCOPE_AGENT);
        while (__hip_atomic_load(&g_bar_g, __ATOMIC_ACQUIRE, __HIP_MEMORY_SCOPE_AGENT)
               < (unsigned)(bar * 8 + 8))
            __builtin_amdgcn_s_sleep(4);
        __threadfence();
    }
    __syncthreads();
}

// ---------------- prep kernels ----------------
__global__ void prep_wc0(const float* __restrict__ Wih, const float* __restrict__ Whh,
                         const float* __restrict__ bih, const float* __restrict__ bhh) {
    int n = blockIdx.x;                 // interleaved row: n = 4h+g
    int h = n >> 2, g = n & 3, r = g * 1024 + h;
    u16* row = g_Wc0 + (size_t)n * KA_;
    for (int j = threadIdx.x; j < KA_; j += 256) {
        float v = (j < 256) ? Wih[(size_t)r * 1281 + j]
                : (j < 1280) ? Wih[(size_t)r * 1281 + j + 1]
                             : Whh[(size_t)r * 1024 + (j - 1280)];
        row[j] = f2b(v);
    }
    if (threadIdx.x == 0) {
        g_wk0[n] = Wih[(size_t)r * 1281 + 256];
        g_pb0[n] = bih[r] + bhh[r];
    }
}

__global__ void prep_wc1(const float* __restrict__ Wih, const float* __restrict__ Whh,
                         const float* __restrict__ bih, const float* __restrict__ bhh) {
    int n = blockIdx.x;
    int h = n >> 2, g = n & 3, r = g * 1024 + h;
    u16* row = g_Wc1 + (size_t)n * KB_;
    for (int j = threadIdx.x; j < KB_; j += 256) {
        float v = (j < 1024) ? Wih[(size_t)r * 1024 + j] : Whh[(size_t)r * 1024 + (j - 1024)];
        row[j] = f2b(v);
    }
    if (threadIdx.x == 0) g_pb1[n] = bih[r] + bhh[r];
}

__global__ void prep_wmq(const float* __restrict__ muW, const float* __restrict__ mub,
                         const float* __restrict__ sgW, const float* __restrict__ sgb) {
    int n = blockIdx.x;                 // n = 2z+sel
    int z = n >> 1, sel = n & 1;
    const float* src = sel ? sgW : muW;
    u16* row = g_Wmq + (size_t)n * 1024;
    for (int j = threadIdx.x; j < 1024; j += 256) row[j] = f2b(src[(size_t)z * 1024 + j]);
    if (threadIdx.x == 0) g_pbmq[n] = sel ? sgb[z] : mub[z];
}

__global__ void prep_copy(const float* __restrict__ in, u16* __restrict__ out, int n) {
    for (int i = blockIdx.x * 256 + threadIdx.x; i < n; i += gridDim.x * 256)
        out[i] = f2b(in[i]);
}

__global__ void prep_winT(const float* __restrict__ Win) {
    __shared__ float t[32][33];
    int bx = blockIdx.x * 32, by = blockIdx.y * 32;
    int tx = threadIdx.x & 31, ty0 = threadIdx.x >> 5;
    for (int it = 0; it < 4; ++it) {
        int ty = ty0 + it * 8;
        t[ty][tx] = Win[(size_t)(by + ty) * 1024 + bx + tx];
    }
    __syncthreads();
    for (int it = 0; it < 4; ++it) {
        int ty = ty0 + it * 8;
        g_WinT[(size_t)(bx + ty) * 1024 + by + tx] = f2b(t[tx][ty]);
    }
}

// ---------------- K-split-4 MFMA quarter-loop (16x16 tile): wave w covers K-quarter ----
template <int K>
__device__ __forceinline__ void mmq(const u16* __restrict__ A, int sA,
                                    const u16* __restrict__ W, int sW,
                                    int m0, int n0, int w, int lane, f32x4& acc) {
    constexpr int KQ = K / 4;
    const int quad = lane >> 4, l16 = lane & 15;
    const u16* pa = A + (size_t)(m0 + l16) * sA + w * KQ + quad * 8;
    const u16* pw = W + (size_t)(n0 + l16) * sW + w * KQ + quad * 8;
#pragma unroll 4
    for (int k0 = 0; k0 < KQ; k0 += 32) {
        short8 a = *(const short8*)(const void*)(pa + k0);
        short8 b = *(const short8*)(const void*)(pw + k0);
        acc = __builtin_amdgcn_mfma_f32_16x16x32_bf16(a, b, acc, 0, 0, 0);
    }
}

// stage one wave's partial 16x16 C-tile into sm[w][16][17]
__device__ __forceinline__ void stage_q(float* sm, int w, int lane, const f32x4& acc) {
    int quad = lane >> 4, l16 = lane & 15;
#pragma unroll
    for (int r = 0; r < 4; ++r) sm[w * 272 + (quad * 4 + r) * 17 + l16] = acc[r];
}

// ---------------- K-split-4 MFMA, 32x32 tile: 4 independent acc chains per wave --------
template <int K>
__device__ __forceinline__ void mm32(const u16* __restrict__ A, int sA,
                                     const u16* __restrict__ W, int sW,
                                     int m0, int n0, int w, int lane, f32x4 acc[2][2]) {
    constexpr int KQ = K / 4;
    const int quad = lane >> 4, l16 = lane & 15;
    const u16* pa0 = A + (size_t)(m0 + l16) * sA + w * KQ + quad * 8;
    const u16* pa1 = pa0 + (size_t)16 * sA;
    const u16* pb0 = W + (size_t)(n0 + l16) * sW + w * KQ + quad * 8;
    const u16* pb1 = pb0 + (size_t)16 * sW;
#pragma unroll 2
    for (int k0 = 0; k0 < KQ; k0 += 32) {
        short8 a0 = *(const short8*)(const void*)(pa0 + k0);
        short8 a1 = *(const short8*)(const void*)(pa1 + k0);
        short8 b0 = *(const short8*)(const void*)(pb0 + k0);
        short8 b1 = *(const short8*)(const void*)(pb1 + k0);
        acc[0][0] = __builtin_amdgcn_mfma_f32_16x16x32_bf16(a0, b0, acc[0][0], 0, 0, 0);
        acc[0][1] = __builtin_amdgcn_mfma_f32_16x16x32_bf16(a0, b1, acc[0][1], 0, 0, 0);
        acc[1][0] = __builtin_amdgcn_mfma_f32_16x16x32_bf16(a1, b0, acc[1][0], 0, 0, 0);
        acc[1][1] = __builtin_amdgcn_mfma_f32_16x16x32_bf16(a1, b1, acc[1][1], 0, 0, 0);
    }
}

// ---------------- persistent-kernel phases ----------------
// lstm: 512 tasks of 32x32 (bid<512); task xcd == physical XCD (bid%8) for L2 reuse
template <int LAYER>
__device__ __forceinline__ void lstm_phase(int bid, int tid, int w, int lane,
                                           float* smf, const int* __restrict__ kvec, int step) {
    if (bid >= 512) return;
    constexpr int K = (LAYER == 0) ? KA_ : KB_;
    const int p = step & 1;
    const u16* A = (LAYER == 0) ? g_XA[p] : g_XB[p];
    const u16* W = (LAYER == 0) ? g_Wc0 : g_Wc1;
    const float* pb = (LAYER == 0) ? g_pb0 : g_pb1;
    float* cs = (LAYER == 0) ? g_cs0 : g_cs1;
    const u16* stOld = (LAYER == 0) ? (g_XA[p] + 1280) : (g_XB[p] + 1024);
    u16* stNew = (LAYER == 0) ? (g_XA[1 - p] + 1280) : (g_XB[1 - p] + 1024);
    u16* hout = (LAYER == 0) ? g_XB[p] : g_XC;
    const int hoStride = (LAYER == 0) ? KB_ : 1024;

    const int xcd = bid & 7, loc = bid >> 3;   // loc 0..63
    const int mt = loc & 3, nl = loc >> 2;     // mt 0..3, nl 0..15
    const int m0 = mt * 32;
    const int n0 = (xcd * 16 + nl) * 32;       // XCD owns fixed 512-col N-slice

    f32x4 acc[2][2] = {};
    mm32<K>(A, K, W, K, m0, n0, w, lane, acc);
    const int quad = lane >> 4, l16 = lane & 15;
#pragma unroll
    for (int i = 0; i < 2; ++i)
#pragma unroll
        for (int j = 0; j < 2; ++j)
#pragma unroll
            for (int r = 0; r < 4; ++r)
                smf[(w * 32 + i * 16 + quad * 4 + r) * 33 + j * 16 + l16] = acc[i][j][r];
    __syncthreads();
    // epilogue: 256 threads = 32 b-rows x 8 h-groups (all threads active)
    const int bl = tid & 31, hl = tid >> 5;
    const int b = m0 + bl;
    float g[4];
#pragma unroll
    for (int gg = 0; gg < 4; ++gg) {
        int c = hl * 4 + gg;
        float s = smf[bl * 33 + c] + smf[(32 + bl) * 33 + c] +
                  smf[(64 + bl) * 33 + c] + smf[(96 + bl) * 33 + c];
        g[gg] = s + pb[n0 + c];
    }
    if (LAYER == 0) {
        float kf = (float)kvec[b];
#pragma unroll
        for (int gg = 0; gg < 4; ++gg) g[gg] += kf * g_wk0[n0 + hl * 4 + gg];
    }
    const int hg = (n0 >> 2) + hl;
    float cold = cs[b * 1024 + hg];
    float cn = sigm(g[1]) * cold + sigm(g[0]) * tanhf(g[2]);
    float hn = sigm(g[3]) * tanhf(cn);
    hout[(size_t)b * hoStride + hg] = f2b(hn);   // unfrozen output
    if (step < kvec[b]) {
        stNew[(size_t)b * K + hg] = f2b(hn);
        cs[b * 1024 + hg] = cn;
    } else {
        stNew[(size_t)b * K + hg] = stOld[(size_t)b * K + hg];
    }
}

// mix: musig (bid<256) | scores+softmax (256..383) | attn q-GEMM -> g_cred (384..895)
__device__ __forceinline__ void mix_phase(int bid, int tid, int w, int lane, float* sm,
                                          const float* __restrict__ eps,
                                          const int* __restrict__ kvec,
                                          float* __restrict__ out,
                                          int step, bool musig, bool sc) {
    if (bid < 256) {
        if (!musig) return;
        const int xcd = bid & 7, loc = bid >> 3;  // loc 0..31
        const int mt = loc & 7, nl = loc >> 3;    // nl 0..3
        const int m0 = mt * 16;
        const int n0 = (xcd * 4 + nl) * 16;       // N=512 total
        f32x4 acc = {0.f, 0.f, 0.f, 0.f};
        mmq<1024>(g_XC, 1024, g_Wmq, 1024, m0, n0, w, lane, acc);
        stage_q(sm, w, lane, acc);
        __syncthreads();
        if (tid < 128) {
            int bl = tid & 15, zl = tid >> 4;  // zl 0..7
            int b = m0 + bl;
            int c0 = 2 * zl, c1 = 2 * zl + 1;
            float mu = sm[bl * 17 + c0] + sm[272 + bl * 17 + c0] +
                       sm[544 + bl * 17 + c0] + sm[816 + bl * 17 + c0] + g_pbmq[n0 + c0];
            float sg = sm[bl * 17 + c1] + sm[272 + bl * 17 + c1] +
                       sm[544 + bl * 17 + c1] + sm[816 + bl * 17 + c1] + g_pbmq[n0 + c1];
            int zg = (n0 >> 1) + zl;
            float e = eps[((size_t)step * B_ + b) * Z_ + zg];
            float zn = mu + expf(sg) * e;
            g_XA[(step + 1) & 1][(size_t)b * KA_ + zg] = f2b(zn);
            bool valid = step < kvec[b];
            size_t o = ((size_t)b * K_ + step) * Z_ + zg;
            out[o] = valid ? zn : 0.f;
            out[BKZ_ + o] = valid ? mu : 0.f;
            out[2 * BKZ_ + o] = valid ? sg : 0.f;
        }
    } else if (bid < 384) {
        if (!sc) return;
        const int b = bid - 256;
        float* qf = sm;                      // [1024]
        float* parts = sm + 1024;            // [64][4]
        for (int i = tid; i < 1024; i += 256) qf[i] = b2f(g_XC[b * 1024 + i]);
        __syncthreads();
        int s = tid >> 2, part = tid & 3;
        const u16* row = g_ctxWin + ((size_t)(b * SRC_ + s)) * 1024 + part * 256;
        float pacc = 0.f;
        for (int j = 0; j < 256; j += 8) {
            short8 v = *(const short8*)(const void*)(row + j);
#pragma unroll
            for (int t = 0; t < 8; ++t) pacc += qf[part * 256 + j + t] * b2f(((u16*)&v)[t]);
        }
        parts[s * 4 + part] = pacc;
        __syncthreads();
        if (tid < 64) {
            float v = parts[tid * 4] + parts[tid * 4 + 1] + parts[tid * 4 + 2] + parts[tid * 4 + 3];
            float mx = v;
            for (int o = 32; o; o >>= 1) mx = fmaxf(mx, __shfl_xor(mx, o, 64));
            float e = expf(v - mx), sum = e;
            for (int o = 32; o; o >>= 1) sum += __shfl_xor(sum, o, 64);
            g_align[b * SRC_ + tid] = e / sum;
        }
    } else if (bid < 896) {
        if (!sc) return;
        const int t = bid - 384;                  // 0..511 ; (t & 7) == bid % 8 (384 % 8 == 0)
        const int xcd = t & 7, loc = t >> 3;      // loc 0..63
        const int mt = loc & 7, nl = loc >> 3;    // nl 0..7
        const int m0 = mt * 16;
        const int n0 = (xcd * 8 + nl) * 16;       // N=1024 total
        f32x4 acc = {0.f, 0.f, 0.f, 0.f};
        mmq<1024>(g_XC, 1024, g_Woutb + 1024, 2048, m0, n0, w, lane, acc);
        stage_q(sm, w, lane, acc);
        __syncthreads();
        int bl = tid >> 4, hc = tid & 15;
        float cred = sm[bl * 17 + hc] + sm[272 + bl * 17 + hc] +
                     sm[544 + bl * 17 + hc] + sm[816 + bl * 17 + hc];
        g_cred[(size_t)(m0 + bl) * 1024 + n0 + hc] = cred;
    }
}

// attn align-contraction: 512 tasks of 16 rows x 16 cols; writes XA[dp] attn columns
__device__ __forceinline__ void contract_phase(int bid, int tid, float* sm, int dp) {
    if (bid >= 512) return;
    const int xcd = bid & 7, loc = bid >> 3;
    const int mt = loc & 7, nl = loc >> 3;
    const int m0 = mt * 16;
    const int n0 = (xcd * 8 + nl) * 16;
    for (int i = tid; i < 16 * SRC_; i += 256)
        sm[i] = g_align[(m0 + (i >> 6)) * SRC_ + (i & 63)];
    __syncthreads();
    int bl = tid >> 4, hc = tid & 15;
    int b = m0 + bl;
    const u16* base = g_ctxW + ((size_t)b * SRC_) * 1024 + n0 + hc;
    float a = g_cred[(size_t)b * 1024 + n0 + hc];
#pragma unroll 8
    for (int s = 0; s < SRC_; ++s) a += sm[bl * 64 + s] * b2f(base[(size_t)s * 1024]);
    g_XA[dp][(size_t)b * KA_ + 256 + n0 + hc] = f2b(tanhf(a));
}

// ---------------- the persistent kernel: entire 48-step loop, 192 grid barriers --------
__global__ __launch_bounds__(256, 4) void k_persist(const float* __restrict__ eps,
                                                    const int* __restrict__ kvec,
                                                    float* __restrict__ out) {
    const int bid = blockIdx.x;
    const int tid = threadIdx.x;
    const int w = tid >> 6, lane = tid & 63;
    __shared__ float smf[4 * 32 * 33];   // 16.9 KB; reused by every phase
    int bar = 0;

    // pre-loop: scores + q-GEMM from XC (= c0[-1]), then attn0 -> XA[0]
    mix_phase(bid, tid, w, lane, smf, eps, kvec, out, 0, false, true);
    gsync(bid, bar); ++bar;
    contract_phase(bid, tid, smf, 0);
    gsync(bid, bar); ++bar;

    for (int i = 0; i < K_; ++i) {
        lstm_phase<0>(bid, tid, w, lane, smf, kvec, i);
        gsync(bid, bar); ++bar;
        lstm_phase<1>(bid, tid, w, lane, smf, kvec, i);
        gsync(bid, bar); ++bar;
        const bool more = (i + 1) < K_;
        mix_phase(bid, tid, w, lane, smf, eps, kvec, out, i, true, more);
        if (more) {
            gsync(bid, bar); ++bar;
            contract_phase(bid, tid, smf, (i + 1) & 1);
            gsync(bid, bar); ++bar;
        }
    }
}

// ---------------- init / final ----------------
__global__ void k_init(const float* __restrict__ h0, const float* __restrict__ c0,
                       const float* __restrict__ z0) {
    int i = blockIdx.x * 256 + threadIdx.x;  // i < BH_
    int b = i >> 10, h = i & 1023;
    g_XA[0][(size_t)b * KA_ + 1280 + h] = f2b(h0[i]);            // h0 layer0 state
    g_XB[0][(size_t)b * KB_ + 1024 + h] = f2b(h0[BH_ + i]);      // h layer1 state
    g_XC[i] = f2b(c0[BH_ + i]);                                  // initial query c0[-1]
    g_cs0[i] = c0[i];
    g_cs1[i] = c0[BH_ + i];
    if (i < BZ_) {
        int bb = i >> 8, z = i & 255;
        g_XA[0][(size_t)bb * KA_ + z] = f2b(z0[i]);
    }
    if (blockIdx.x == 0 && threadIdx.x == 0) {   // reset grid-barrier state
        g_bar_g = 0;
        for (int x = 0; x < 8; ++x) g_bar_x[x][0] = 0;
    }
}

__global__ void k_final(float* __restrict__ out) {
    int i = blockIdx.x * 256 + threadIdx.x;  // i < BH_
    int b = i >> 10, h = i & 1023;
    float* hf = out + (size_t)3 * BKZ_;
    float* cf = hf + 2 * BH_;
    hf[i] = b2f(g_XA[0][(size_t)b * KA_ + 1280 + h]);
    hf[BH_ + i] = b2f(g_XB[0][(size_t)b * KB_ + 1024 + h]);
    cf[i] = g_cs0[i];
    cf[BH_ + i] = g_cs1[i];
}

// ---------------- prep GEMM: Out[m][n] = sum_k A[m][k]*W[n][k], 128x64 tiles -----------
// 1-D grid 1024, XCD-swizzled: each XCD owns a 128-col W slice (L2-resident) and
// streams A once; adjacent blocks (same XCD) share an A-tile.
__global__ __launch_bounds__(256) void k_gemm_prep(const u16* __restrict__ A, int sA,
                                                   const u16* __restrict__ W, int sW,
                                                   u16* __restrict__ Out, int sO) {
    const int tid = threadIdx.x, w = tid >> 6, lane = tid & 63;
    const int quad = lane >> 4, l16 = lane & 15;
    const int xcd = blockIdx.x & 7, loc = blockIdx.x >> 3;   // loc 0..127
    const int n0 = (xcd * 2 + (loc & 1)) * 64;               // XCD-fixed 128-col slice
    const int mb = (loc >> 1) * 128 + w * 32;                // 64 m-tiles, streamed
    f32x4 acc[2][4] = {};
    const u16* pa0 = A + (size_t)(mb + l16) * sA + quad * 8;
    const u16* pa1 = pa0 + (size_t)16 * sA;
    const u16* pw = W + (size_t)(n0 + l16) * sW + quad * 8;
#pragma unroll 2
    for (int k0 = 0; k0 < 1024; k0 += 32) {
        short8 a0 = *(const short8*)(const void*)(pa0 + k0);
        short8 a1 = *(const short8*)(const void*)(pa1 + k0);
#pragma unroll
        for (int j = 0; j < 4; ++j) {
            short8 b = *(const short8*)(const void*)(pw + (size_t)j * 16 * sW + k0);
            acc[0][j] = __builtin_amdgcn_mfma_f32_16x16x32_bf16(a0, b, acc[0][j], 0, 0, 0);
            acc[1][j] = __builtin_amdgcn_mfma_f32_16x16x32_bf16(a1, b, acc[1][j], 0, 0, 0);
        }
    }
#pragma unroll
    for (int i = 0; i < 2; ++i)
#pragma unroll
        for (int j = 0; j < 4; ++j)
#pragma unroll
            for (int r = 0; r < 4; ++r)
                Out[(size_t)(mb + i * 16 + quad * 4 + r) * sO + n0 + j * 16 + l16] =
                    f2b(acc[i][j][r]);
}

extern "C" void kernel_launch(void* const* d_in, const int* in_sizes, int n_in,
                              void* d_out, int out_size, void* d_ws, size_t ws_size,
                              hipStream_t stream) {
    (void)in_sizes; (void)n_in; (void)out_size; (void)d_ws; (void)ws_size;
    const float* h0 = (const float*)d_in[0];
    const float* c0 = (const float*)d_in[1];
    const float* ctx = (const float*)d_in[2];
    const float* z0 = (const float*)d_in[3];
    const int* kvec = (const int*)d_in[4];
    const float* eps = (const float*)d_in[5];
    const float* Wih0 = (const float*)d_in[6];
    const float* Whh0 = (const float*)d_in[7];
    const float* bih0 = (const float*)d_in[8];
    const float* bhh0 = (const float*)d_in[9];
    const float* Wih1 = (const float*)d_in[10];
    const float* Whh1 = (const float*)d_in[11];
    const float* bih1 = (const float*)d_in[12];
    const float* bhh1 = (const float*)d_in[13];
    const float* Win = (const float*)d_in[14];
    const float* Wout = (const float*)d_in[15];
    const float* muW = (const float*)d_in[16];
    const float* mub = (const float*)d_in[17];
    const float* sgW = (const float*)d_in[18];
    const float* sgb = (const float*)d_in[19];
    float* out = (float*)d_out;

    dim3 blk(256);
    // ---- one-time prep ----
    prep_wc0<<<4096, blk, 0, stream>>>(Wih0, Whh0, bih0, bhh0);
    prep_wc1<<<4096, blk, 0, stream>>>(Wih1, Whh1, bih1, bhh1);
    prep_wmq<<<512, blk, 0, stream>>>(muW, mub, sgW, sgb);
    {
        u16* woutb; hipGetSymbolAddress((void**)&woutb, HIP_SYMBOL(g_Woutb));
        u16* ctxb; hipGetSymbolAddress((void**)&ctxb, HIP_SYMBOL(g_ctxb));
        u16* winT; hipGetSymbolAddress((void**)&winT, HIP_SYMBOL(g_WinT));
        u16* ctxW; hipGetSymbolAddress((void**)&ctxW, HIP_SYMBOL(g_ctxW));
        u16* ctxWin; hipGetSymbolAddress((void**)&ctxWin, HIP_SYMBOL(g_ctxWin));
        prep_copy<<<2048, blk, 0, stream>>>(Wout, woutb, 1024 * 2048);
        prep_copy<<<8192, blk, 0, stream>>>(ctx, ctxb, 8192 * 1024);
        prep_winT<<<dim3(32, 32), blk, 0, stream>>>(Win);
        // ctxW = ctx @ Wout[:, :1024]^T ; ctxWin = ctx @ Win
        k_gemm_prep<<<1024, blk, 0, stream>>>(ctxb, 1024, woutb, 2048, ctxW, 1024);
        k_gemm_prep<<<1024, blk, 0, stream>>>(ctxb, 1024, winT, 1024, ctxWin, 1024);
    }
    // ---- init state (+ barrier reset), then the whole 48-step loop in ONE kernel ----
    k_init<<<BH_ / 256, blk, 0, stream>>>(h0, c0, z0);
    k_persist<<<NBLK_, blk, 0, stream>>>(eps, kvec, out);
    k_final<<<BH_ / 256, blk, 0, stream>>>(out);
}

// Round 2
// 3213.248 us; speedup vs baseline: 14.0796x; 14.0796x over previous
//
#include <hip/hip_runtime.h>
#include <hip/hip_bf16.h>

#define L_ 2
#define H_ 1024
#define Z_ 256
#define B_ 128
#define SRC_ 64
#define K_ 48
#define BH_ (B_ * H_)
#define BZ_ (B_ * Z_)
#define BKZ_ ((size_t)B_ * K_ * Z_)
#define KA_ 2304   // lstm0 GEMM K: z(256) | attn(1024) | h0(1024)
#define KB_ 2048   // lstm1 GEMM K: h0n(1024) | h1(1024)

typedef unsigned short u16;
typedef __attribute__((ext_vector_type(8))) short short8;
typedef __attribute__((ext_vector_type(4))) float f32x4;

// ---------------- static device workspace ----------------
__device__ __align__(16) u16 g_Wc0[4096 * KA_];     // lstm0 weights [4h+g][KA]
__device__ __align__(16) u16 g_Wc1[4096 * KB_];     // lstm1 weights
__device__ __align__(16) u16 g_Wmq[512 * 1024];     // mu/sigma rows interleaved [2z+sel][1024]
__device__ __align__(16) u16 g_Woutb[1024 * 2048];  // Wout bf16
__device__ __align__(16) u16 g_WinT[1024 * 1024];   // Win transposed bf16
__device__ __align__(16) u16 g_ctxb[8192 * 1024];   // context bf16 [B*SRC][H]
__device__ __align__(16) u16 g_ctxW[8192 * 1024];   // ctx @ Wout[:, :H]^T
__device__ __align__(16) u16 g_ctxWin[8192 * 1024]; // ctx @ Win
__device__ __align__(16) u16 g_XA[2][B_ * KA_];     // lstm0 input (dbl-buf): z|attn|h0state  [row-permuted]
__device__ __align__(16) u16 g_XB[2][B_ * KB_];     // lstm1 input: h0n|h1state               [row-permuted]
__device__ __align__(16) u16 g_XC[B_ * H_];         // h1n unfrozen (query / musig input)     [row-permuted]
__device__ float g_pb0[4096], g_pb1[4096], g_pbmq[512], g_wk0[4096];
__device__ float g_cs0[BH_], g_cs1[BH_], g_align[B_ * SRC_];
__device__ float g_cred[B_ * H_];                   // attn q-GEMM staging (fp32)  [row-permuted]
// k-sort state: rows sorted by k descending; row r holds batch element g_perm[r]
__device__ int g_perm[B_], g_inv[B_], g_kr[B_], g_Mact[K_];

__device__ __forceinline__ float sigm(float x) { return 1.0f / (1.0f + expf(-x)); }
__device__ __forceinline__ u16 f2b(float f) {
    union { float f; unsigned u; } x; x.f = f;
    unsigned r = x.u + 0x7fffu + ((x.u >> 16) & 1u);
    return (u16)(r >> 16);
}
__device__ __forceinline__ float b2f(u16 s) {
    union { unsigned u; float f; } x; x.u = ((unsigned)s) << 16;
    return x.f;
}

// ---------------- sort rows by k descending; Mact[i] = #rows live at step i ------------
__global__ void k_sort(const int* __restrict__ kvec) {
    __shared__ int ks[B_];
    int t = threadIdx.x;
    if (t < B_) ks[t] = kvec[t];
    __syncthreads();
    if (t < B_) {
        int kb = ks[t], rank = 0;
        for (int j = 0; j < B_; ++j) { int kj = ks[j]; rank += (kj > kb) || (kj == kb && j < t); }
        g_perm[rank] = t; g_inv[t] = rank; g_kr[rank] = kb;
    }
    if (t < K_) { int c = 0; for (int j = 0; j < B_; ++j) c += (ks[j] > t); g_Mact[t] = c; }
}

__global__ void k_zero(float* __restrict__ out) {
    size_t n = 3 * BKZ_;
    for (size_t i = (size_t)blockIdx.x * 256 + threadIdx.x; i < n; i += (size_t)gridDim.x * 256)
        out[i] = 0.f;
}

// ---------------- prep kernels ----------------
__global__ void prep_wc0(const float* __restrict__ Wih, const float* __restrict__ Whh,
                         const float* __restrict__ bih, const float* __restrict__ bhh) {
    int n = blockIdx.x;                 // interleaved row: n = 4h+g
    int h = n >> 2, g = n & 3, r = g * 1024 + h;
    u16* row = g_Wc0 + (size_t)n * KA_;
    for (int j = threadIdx.x; j < KA_; j += 256) {
        float v = (j < 256) ? Wih[(size_t)r * 1281 + j]
                : (j < 1280) ? Wih[(size_t)r * 1281 + j + 1]
                             : Whh[(size_t)r * 1024 + (j - 1280)];
        row[j] = f2b(v);
    }
    if (threadIdx.x == 0) {
        g_wk0[n] = Wih[(size_t)r * 1281 + 256];
        g_pb0[n] = bih[r] + bhh[r];
    }
}

__global__ void prep_wc1(const float* __restrict__ Wih, const float* __restrict__ Whh,
                         const float* __restrict__ bih, const float* __restrict__ bhh) {
    int n = blockIdx.x;
    int h = n >> 2, g = n & 3, r = g * 1024 + h;
    u16* row = g_Wc1 + (size_t)n * KB_;
    for (int j = threadIdx.x; j < KB_; j += 256) {
        float v = (j < 1024) ? Wih[(size_t)r * 1024 + j] : Whh[(size_t)r * 1024 + (j - 1024)];
        row[j] = f2b(v);
    }
    if (threadIdx.x == 0) g_pb1[n] = bih[r] + bhh[r];
}

__global__ void prep_wmq(const float* __restrict__ muW, const float* __restrict__ mub,
                         const float* __restrict__ sgW, const float* __restrict__ sgb) {
    int n = blockIdx.x;                 // n = 2z+sel
    int z = n >> 1, sel = n & 1;
    const float* src = sel ? sgW : muW;
    u16* row = g_Wmq + (size_t)n * 1024;
    for (int j = threadIdx.x; j < 1024; j += 256) row[j] = f2b(src[(size_t)z * 1024 + j]);
    if (threadIdx.x == 0) g_pbmq[n] = sel ? sgb[z] : mub[z];
}

__global__ void prep_copy(const float* __restrict__ in, u16* __restrict__ out, int n) {
    for (int i = blockIdx.x * 256 + threadIdx.x; i < n; i += gridDim.x * 256)
        out[i] = f2b(in[i]);
}

__global__ void prep_winT(const float* __restrict__ Win) {
    __shared__ float t[32][33];
    int bx = blockIdx.x * 32, by = blockIdx.y * 32;
    int tx = threadIdx.x & 31, ty0 = threadIdx.x >> 5;
    for (int it = 0; it < 4; ++it) {
        int ty = ty0 + it * 8;
        t[ty][tx] = Win[(size_t)(by + ty) * 1024 + bx + tx];
    }
    __syncthreads();
    for (int it = 0; it < 4; ++it) {
        int ty = ty0 + it * 8;
        g_WinT[(size_t)(bx + ty) * 1024 + by + tx] = f2b(t[tx][ty]);
    }
}

// ---------------- K-split-4 MFMA quarter-loop (16x16 tile): wave w covers K-quarter ----
template <int K>
__device__ __forceinline__ void mmq(const u16* __restrict__ A, int sA,
                                    const u16* __restrict__ W, int sW,
                                    int m0, int n0, int w, int lane, f32x4& acc) {
    constexpr int KQ = K / 4;
    const int quad = lane >> 4, l16 = lane & 15;
    const u16* pa = A + (size_t)(m0 + l16) * sA + w * KQ + quad * 8;
    const u16* pw = W + (size_t)(n0 + l16) * sW + w * KQ + quad * 8;
#pragma unroll 4
    for (int k0 = 0; k0 < KQ; k0 += 32) {
        short8 a = *(const short8*)(const void*)(pa + k0);
        short8 b = *(const short8*)(const void*)(pw + k0);
        acc = __builtin_amdgcn_mfma_f32_16x16x32_bf16(a, b, acc, 0, 0, 0);
    }
}

// stage one wave's partial 16x16 C-tile into sm[w][16][17]
__device__ __forceinline__ void stage_q(float* sm, int w, int lane, const f32x4& acc) {
    int quad = lane >> 4, l16 = lane & 15;
#pragma unroll
    for (int r = 0; r < 4; ++r) sm[w * 272 + (quad * 4 + r) * 17 + l16] = acc[r];
}

// ---------------- K-split-4 MFMA, 32x32 tile: 4 independent acc chains per wave --------
template <int K>
__device__ __forceinline__ void mm32(const u16* __restrict__ A, int sA,
                                     const u16* __restrict__ W, int sW,
                                     int m0, int n0, int w, int lane, f32x4 acc[2][2]) {
    constexpr int KQ = K / 4;
    const int quad = lane >> 4, l16 = lane & 15;
    const u16* pa0 = A + (size_t)(m0 + l16) * sA + w * KQ + quad * 8;
    const u16* pa1 = pa0 + (size_t)16 * sA;
    const u16* pb0 = W + (size_t)(n0 + l16) * sW + w * KQ + quad * 8;
    const u16* pb1 = pb0 + (size_t)16 * sW;
#pragma unroll 2
    for (int k0 = 0; k0 < KQ; k0 += 32) {
        short8 a0 = *(const short8*)(const void*)(pa0 + k0);
        short8 a1 = *(const short8*)(const void*)(pa1 + k0);
        short8 b0 = *(const short8*)(const void*)(pb0 + k0);
        short8 b1 = *(const short8*)(const void*)(pb1 + k0);
        acc[0][0] = __builtin_amdgcn_mfma_f32_16x16x32_bf16(a0, b0, acc[0][0], 0, 0, 0);
        acc[0][1] = __builtin_amdgcn_mfma_f32_16x16x32_bf16(a0, b1, acc[0][1], 0, 0, 0);
        acc[1][0] = __builtin_amdgcn_mfma_f32_16x16x32_bf16(a1, b0, acc[1][0], 0, 0, 0);
        acc[1][1] = __builtin_amdgcn_mfma_f32_16x16x32_bf16(a1, b1, acc[1][1], 0, 0, 0);
    }
}

// ---------------- LSTM GEMM+cell, 32x32 tiles, grid 512 = 8 xcd x (4 mt x 16 nl) -------
// M trimmed to Mact(step): fully-frozen tiles only carry state.
template <int LAYER>
__global__ __launch_bounds__(256) void k_lstm(int step) {
    constexpr int K = (LAYER == 0) ? KA_ : KB_;
    const int p = step & 1;
    const u16* A = (LAYER == 0) ? g_XA[p] : g_XB[p];
    const u16* W = (LAYER == 0) ? g_Wc0 : g_Wc1;
    const float* pb = (LAYER == 0) ? g_pb0 : g_pb1;
    float* cs = (LAYER == 0) ? g_cs0 : g_cs1;
    const u16* stOld = (LAYER == 0) ? (g_XA[p] + 1280) : (g_XB[p] + 1024);
    u16* stNew = (LAYER == 0) ? (g_XA[1 - p] + 1280) : (g_XB[1 - p] + 1024);
    u16* hout = (LAYER == 0) ? g_XB[p] : g_XC;
    const int hoStride = (LAYER == 0) ? KB_ : 1024;

    const int tid = threadIdx.x, w = tid >> 6, lane = tid & 63;
    const int xcd = blockIdx.x & 7, loc = blockIdx.x >> 3;   // loc 0..63
    const int mt = loc & 3, nl = loc >> 2;                   // mt 0..3, nl 0..15
    const int m0 = mt * 32;
    const int n0 = (xcd * 16 + nl) * 32;                     // XCD owns fixed 512-col N-slice
    const int Mact = g_Mact[step];

    if (m0 >= Mact) {   // all 32 rows frozen: carry state (32 rows x 8 cols = 256 threads)
        const int r = m0 + (tid & 31), hg = (n0 >> 2) + (tid >> 5);
        stNew[(size_t)r * K + hg] = stOld[(size_t)r * K + hg];
        return;
    }

    __shared__ float smf[4 * 32 * 33];
    f32x4 acc[2][2] = {};
    mm32<K>(A, K, W, K, m0, n0, w, lane, acc);
    const int quad = lane >> 4, l16 = lane & 15;
#pragma unroll
    for (int i = 0; i < 2; ++i)
#pragma unroll
        for (int j = 0; j < 2; ++j)
#pragma unroll
            for (int r = 0; r < 4; ++r)
                smf[(w * 32 + i * 16 + quad * 4 + r) * 33 + j * 16 + l16] = acc[i][j][r];
    __syncthreads();
    // epilogue: 256 threads = 32 rows x 8 h-groups
    const int bl = tid & 31, hl = tid >> 5;
    const int r = m0 + bl;
    float g[4];
#pragma unroll
    for (int gg = 0; gg < 4; ++gg) {
        int c = hl * 4 + gg;
        float s = smf[bl * 33 + c] + smf[(32 + bl) * 33 + c] +
                  smf[(64 + bl) * 33 + c] + smf[(96 + bl) * 33 + c];
        g[gg] = s + pb[n0 + c];
    }
    const int kr = g_kr[r];
    if (LAYER == 0) {
        float kf = (float)kr;
#pragma unroll
        for (int gg = 0; gg < 4; ++gg) g[gg] += kf * g_wk0[n0 + hl * 4 + gg];
    }
    const int hg = (n0 >> 2) + hl;
    float cold = cs[r * 1024 + hg];
    float cn = sigm(g[1]) * cold + sigm(g[0]) * tanhf(g[2]);
    float hn = sigm(g[3]) * tanhf(cn);
    hout[(size_t)r * hoStride + hg] = f2b(hn);   // unfrozen output
    if (step < kr) {
        stNew[(size_t)r * K + hg] = f2b(hn);
        cs[r * 1024 + hg] = cn;
    } else {
        stNew[(size_t)r * K + hg] = stOld[(size_t)r * K + hg];
    }
}

// ---- mix: musig (0..255) | scores+softmax (256..383) | attn q-GEMM -> cred (384..895) --
__global__ __launch_bounds__(256) void k_mix(const float* __restrict__ eps,
                                             float* __restrict__ out, int step,
                                             int do_mu, int do_sc) {
    __shared__ float sm[1344];
    const int tid = threadIdx.x;
    const int Mact = g_Mact[step];
    if (blockIdx.x < 256) {
        if (!do_mu) return;
        const int w = tid >> 6, lane = tid & 63;
        const int xcd = blockIdx.x & 7, loc = blockIdx.x >> 3;  // loc 0..31
        const int mt = loc & 7, nl = loc >> 3;                  // nl 0..3
        const int m0 = mt * 16;
        const int n0 = (xcd * 4 + nl) * 16;                     // N=512 total
        if (m0 >= Mact) return;                                 // frozen tile: out prezeroed
        f32x4 acc = {0.f, 0.f, 0.f, 0.f};
        mmq<1024>(g_XC, 1024, g_Wmq, 1024, m0, n0, w, lane, acc);
        stage_q(sm, w, lane, acc);
        __syncthreads();
        if (tid < 128) {
            int bl = tid & 15, zl = tid >> 4;  // zl 0..7
            int r = m0 + bl;
            int c0 = 2 * zl, c1 = 2 * zl + 1;
            float mu = sm[bl * 17 + c0] + sm[272 + bl * 17 + c0] +
                       sm[544 + bl * 17 + c0] + sm[816 + bl * 17 + c0] + g_pbmq[n0 + c0];
            float sg = sm[bl * 17 + c1] + sm[272 + bl * 17 + c1] +
                       sm[544 + bl * 17 + c1] + sm[816 + bl * 17 + c1] + g_pbmq[n0 + c1];
            int zg = (n0 >> 1) + zl;
            int b = g_perm[r];
            float e = eps[((size_t)step * B_ + b) * Z_ + zg];
            float zn = mu + expf(sg) * e;
            g_XA[(step + 1) & 1][(size_t)r * KA_ + zg] = f2b(zn);
            bool valid = step < g_kr[r];
            size_t o = ((size_t)b * K_ + step) * Z_ + zg;
            out[o] = valid ? zn : 0.f;
            out[BKZ_ + o] = valid ? mu : 0.f;
            out[2 * BKZ_ + o] = valid ? sg : 0.f;
        }
    } else if (blockIdx.x < 384) {
        if (!do_sc) return;
        const int r = blockIdx.x - 256;      // sorted row
        if (r >= Mact) return;
        float* qf = sm;                      // [1024]
        float* parts = sm + 1024;            // [64][4]
        for (int i = tid; i < 1024; i += 256) qf[i] = b2f(g_XC[r * 1024 + i]);
        __syncthreads();
        int s = tid >> 2, part = tid & 3;
        const int b = g_perm[r];
        const u16* row = g_ctxWin + ((size_t)(b * SRC_ + s)) * 1024 + part * 256;
        float pacc = 0.f;
        for (int j = 0; j < 256; j += 8) {
            short8 v = *(const short8*)(const void*)(row + j);
#pragma unroll
            for (int t = 0; t < 8; ++t) pacc += qf[part * 256 + j + t] * b2f(((u16*)&v)[t]);
        }
        parts[s * 4 + part] = pacc;
        __syncthreads();
        if (tid < 64) {
            float v = parts[tid * 4] + parts[tid * 4 + 1] + parts[tid * 4 + 2] + parts[tid * 4 + 3];
            float mx = v;
            for (int o = 32; o; o >>= 1) mx = fmaxf(mx, __shfl_xor(mx, o, 64));
            float e = expf(v - mx), sum = e;
            for (int o = 32; o; o >>= 1) sum += __shfl_xor(sum, o, 64);
            g_align[r * SRC_ + tid] = e / sum;
        }
    } else {
        if (!do_sc) return;
        const int w = tid >> 6, lane = tid & 63;
        const int t = blockIdx.x - 384;           // 0..511
        const int xcd = t & 7, loc = t >> 3;      // loc 0..63
        const int mt = loc & 7, nl = loc >> 3;    // nl 0..7
        const int m0 = mt * 16;
        const int n0 = (xcd * 8 + nl) * 16;       // N=1024 total
        if (m0 >= Mact) return;
        f32x4 acc = {0.f, 0.f, 0.f, 0.f};
        mmq<1024>(g_XC, 1024, g_Woutb + 1024, 2048, m0, n0, w, lane, acc);
        stage_q(sm, w, lane, acc);
        __syncthreads();
        int bl = tid >> 4, hc = tid & 15;
        float cred = sm[bl * 17 + hc] + sm[272 + bl * 17 + hc] +
                     sm[544 + bl * 17 + hc] + sm[816 + bl * 17 + hc];
        g_cred[(size_t)(m0 + bl) * 1024 + n0 + hc] = cred;
    }
}

// ---- attn align-contraction: light, 512 blocks of 16 rows x 16 cols; writes XA[dp] ----
__global__ __launch_bounds__(256) void k_contract(int dp, int step) {
    __shared__ float sm[16 * SRC_];
    const int tid = threadIdx.x;
    const int xcd = blockIdx.x & 7, loc = blockIdx.x >> 3;
    const int mt = loc & 7, nl = loc >> 3;
    const int m0 = mt * 16;
    const int n0 = (xcd * 8 + nl) * 16;
    if (m0 >= g_Mact[step]) return;
    for (int i = tid; i < 16 * SRC_; i += 256)
        sm[i] = g_align[(m0 + (i >> 6)) * SRC_ + (i & 63)];
    __syncthreads();
    int bl = tid >> 4, hc = tid & 15;
    int r = m0 + bl;
    const int b = g_perm[r];
    const u16* base = g_ctxW + ((size_t)b * SRC_) * 1024 + n0 + hc;
    float a = g_cred[(size_t)r * 1024 + n0 + hc];
#pragma unroll 8
    for (int s = 0; s < SRC_; ++s) a += sm[bl * 64 + s] * b2f(base[(size_t)s * 1024]);
    g_XA[dp][(size_t)r * KA_ + 256 + n0 + hc] = f2b(tanhf(a));
}

// ---------------- init / final (row-permuted) ----------------
__global__ void k_init(const float* __restrict__ h0, const float* __restrict__ c0,
                       const float* __restrict__ z0) {
    int i = blockIdx.x * 256 + threadIdx.x;  // i < BH_
    int b = i >> 10, h = i & 1023;
    int r = g_inv[b];
    g_XA[0][(size_t)r * KA_ + 1280 + h] = f2b(h0[i]);            // h0 layer0 state
    g_XB[0][(size_t)r * KB_ + 1024 + h] = f2b(h0[BH_ + i]);      // h layer1 state
    g_XC[r * 1024 + h] = f2b(c0[BH_ + i]);                       // initial query c0[-1]
    g_cs0[r * 1024 + h] = c0[i];
    g_cs1[r * 1024 + h] = c0[BH_ + i];
    if (i < BZ_) {
        int bb = i >> 8, z = i & 255;
        g_XA[0][(size_t)g_inv[bb] * KA_ + z] = f2b(z0[i]);
    }
}

__global__ void k_final(float* __restrict__ out) {
    int i = blockIdx.x * 256 + threadIdx.x;  // i < BH_
    int b = i >> 10, h = i & 1023;
    int r = g_inv[b];
    float* hf = out + (size_t)3 * BKZ_;
    float* cf = hf + 2 * BH_;
    hf[i] = b2f(g_XA[0][(size_t)r * KA_ + 1280 + h]);
    hf[BH_ + i] = b2f(g_XB[0][(size_t)r * KB_ + 1024 + h]);
    cf[i] = g_cs0[r * 1024 + h];
    cf[BH_ + i] = g_cs1[r * 1024 + h];
}

// ---------------- prep GEMM: Out[m][n] = sum_k A[m][k]*W[n][k], 128x64 tiles -----------
__global__ __launch_bounds__(256) void k_gemm_prep(const u16* __restrict__ A, int sA,
                                                   const u16* __restrict__ W, int sW,
                                                   u16* __restrict__ Out, int sO) {
    const int tid = threadIdx.x, w = tid >> 6, lane = tid & 63;
    const int quad = lane >> 4, l16 = lane & 15;
    const int xcd = blockIdx.x & 7, loc = blockIdx.x >> 3;   // loc 0..127
    const int n0 = (xcd * 2 + (loc & 1)) * 64;               // XCD-fixed 128-col slice
    const int mb = (loc >> 1) * 128 + w * 32;                // 64 m-tiles, streamed
    f32x4 acc[2][4] = {};
    const u16* pa0 = A + (size_t)(mb + l16) * sA + quad * 8;
    const u16* pa1 = pa0 + (size_t)16 * sA;
    const u16* pw = W + (size_t)(n0 + l16) * sW + quad * 8;
#pragma unroll 2
    for (int k0 = 0; k0 < 1024; k0 += 32) {
        short8 a0 = *(const short8*)(const void*)(pa0 + k0);
        short8 a1 = *(const short8*)(const void*)(pa1 + k0);
#pragma unroll
        for (int j = 0; j < 4; ++j) {
            short8 b = *(const short8*)(const void*)(pw + (size_t)j * 16 * sW + k0);
            acc[0][j] = __builtin_amdgcn_mfma_f32_16x16x32_bf16(a0, b, acc[0][j], 0, 0, 0);
            acc[1][j] = __builtin_amdgcn_mfma_f32_16x16x32_bf16(a1, b, acc[1][j], 0, 0, 0);
        }
    }
#pragma unroll
    for (int i = 0; i < 2; ++i)
#pragma unroll
        for (int j = 0; j < 4; ++j)
#pragma unroll
            for (int r = 0; r < 4; ++r)
                Out[(size_t)(mb + i * 16 + quad * 4 + r) * sO + n0 + j * 16 + l16] =
                    f2b(acc[i][j][r]);
}

extern "C" void kernel_launch(void* const* d_in, const int* in_sizes, int n_in,
                              void* d_out, int out_size, void* d_ws, size_t ws_size,
                              hipStream_t stream) {
    (void)in_sizes; (void)n_in; (void)out_size; (void)d_ws; (void)ws_size;
    const float* h0 = (const float*)d_in[0];
    const float* c0 = (const float*)d_in[1];
    const float* ctx = (const float*)d_in[2];
    const float* z0 = (const float*)d_in[3];
    const int* kvec = (const int*)d_in[4];
    const float* eps = (const float*)d_in[5];
    const float* Wih0 = (const float*)d_in[6];
    const float* Whh0 = (const float*)d_in[7];
    const float* bih0 = (const float*)d_in[8];
    const float* bhh0 = (const float*)d_in[9];
    const float* Wih1 = (const float*)d_in[10];
    const float* Whh1 = (const float*)d_in[11];
    const float* bih1 = (const float*)d_in[12];
    const float* bhh1 = (const float*)d_in[13];
    const float* Win = (const float*)d_in[14];
    const float* Wout = (const float*)d_in[15];
    const float* muW = (const float*)d_in[16];
    const float* mub = (const float*)d_in[17];
    const float* sgW = (const float*)d_in[18];
    const float* sgb = (const float*)d_in[19];
    float* out = (float*)d_out;

    dim3 blk(256);
    // ---- one-time prep ----
    k_sort<<<1, 128, 0, stream>>>(kvec);
    k_zero<<<2048, blk, 0, stream>>>(out);
    prep_wc0<<<4096, blk, 0, stream>>>(Wih0, Whh0, bih0, bhh0);
    prep_wc1<<<4096, blk, 0, stream>>>(Wih1, Whh1, bih1, bhh1);
    prep_wmq<<<512, blk, 0, stream>>>(muW, mub, sgW, sgb);
    {
        u16* woutb; hipGetSymbolAddress((void**)&woutb, HIP_SYMBOL(g_Woutb));
        u16* ctxb; hipGetSymbolAddress((void**)&ctxb, HIP_SYMBOL(g_ctxb));
        u16* winT; hipGetSymbolAddress((void**)&winT, HIP_SYMBOL(g_WinT));
        u16* ctxW; hipGetSymbolAddress((void**)&ctxW, HIP_SYMBOL(g_ctxW));
        u16* ctxWin; hipGetSymbolAddress((void**)&ctxWin, HIP_SYMBOL(g_ctxWin));
        prep_copy<<<2048, blk, 0, stream>>>(Wout, woutb, 1024 * 2048);
        prep_copy<<<8192, blk, 0, stream>>>(ctx, ctxb, 8192 * 1024);
        prep_winT<<<dim3(32, 32), blk, 0, stream>>>(Win);
        // ctxW = ctx @ Wout[:, :1024]^T ; ctxWin = ctx @ Win
        k_gemm_prep<<<1024, blk, 0, stream>>>(ctxb, 1024, woutb, 2048, ctxW, 1024);
        k_gemm_prep<<<1024, blk, 0, stream>>>(ctxb, 1024, winT, 1024, ctxWin, 1024);
    }
    // ---- init state (row-permuted) + initial attention (q = c0[-1]) ----
    k_init<<<BH_ / 256, blk, 0, stream>>>(h0, c0, z0);
    k_mix<<<896, blk, 0, stream>>>(eps, out, 0, 0, 1);        // scores + q-GEMM only
    k_contract<<<512, blk, 0, stream>>>(0, 0);                // attn0 -> XA[0]

    // ---- 48 steps ----
    for (int i = 0; i < K_; ++i) {
        k_lstm<0><<<512, blk, 0, stream>>>(i);
        k_lstm<1><<<512, blk, 0, stream>>>(i);
        const int more = (i + 1 < K_) ? 1 : 0;
        k_mix<<<896, blk, 0, stream>>>(eps, out, i, 1, more);
        if (more) k_contract<<<512, blk, 0, stream>>>((i + 1) & 1, i);
    }
    // K_=48 even -> final states in parity-0 buffers
    k_final<<<BH_ / 256, blk, 0, stream>>>(out);
}